// Round 1
// baseline (473.747 us; speedup 1.0000x reference)
//
#include <hip/hip_runtime.h>

// upfirdn2d, depthwise 4x4 blur, kernel = outer([1,3,3,1],[1,3,3,1])/64.
// x: (16,256,128,128) f32  ->  out: (16,256,127,127) f32, pad (1,1)/(1,1).
// Memory-bound: ~530 MB compulsory traffic -> ~84 us ideal at 6.3 TB/s.
//
// Structure: 1 block (128 threads) per (n,c) image; thread = output column.
// Horizontal 4-tap read directly from global (contiguous lanes -> halo reads
// are L1 hits), vertical 4-tap via rolling registers. No LDS, no barriers.

#define IH 128
#define IW 128
#define OH 127
#define OW 127

__global__ __launch_bounds__(128)
void upfirdn2d_blur_kernel(const float* __restrict__ x, float* __restrict__ out) {
    const int img = blockIdx.x;            // 0..4095  (n*256 + c)
    const int tx  = threadIdx.x;           // 0..127

    const float* __restrict__ in = x   + (size_t)img * (IH * IW);
    float*       __restrict__ o  = out + (size_t)img * (OH * OW);

    const bool active = (tx < OW);         // tx==127 computes garbage, never stores

    // Clamped taps + {0,1} masks: no divergent loads, no OOB addresses.
    const float mL = (tx >= 1)      ? 1.0f : 0.0f;   // x-1 tap valid?
    const float mR = (tx + 2 < IW)  ? 1.0f : 0.0f;   // x+2 tap valid?
    const int xl = (tx >= 1)      ? tx - 1 : 0;
    const int x1 = (tx + 1 < IW)  ? tx + 1 : IW - 1; // only clamps for inactive tx==127
    const int xr = (tx + 2 < IW)  ? tx + 2 : IW - 1;

    auto hrow = [&](int r) -> float {
        const float* __restrict__ p = in + r * IW;
        // unnormalized horizontal 4-tap: 1,3,3,1
        return mL * p[xl] + 3.0f * (p[tx] + p[x1]) + mR * p[xr];
    };

    // rolling vertical window: out[y] = (h[y-1] + 3h[y] + 3h[y+1] + h[y+2]) / 64
    float hm1 = 0.0f;          // h(-1) = 0 (top zero pad)
    float h0  = hrow(0);
    float h1  = hrow(1);

    #pragma unroll 2
    for (int y = 0; y < OH - 1; ++y) {     // y = 0..125, reads rows y+2 = 2..127
        const float h2 = hrow(y + 2);
        if (active)
            o[y * OW + tx] = (hm1 + 3.0f * (h0 + h1) + h2) * 0.015625f;
        hm1 = h0; h0 = h1; h1 = h2;
    }
    // y = 126: h(128) = 0 (bottom zero pad)
    if (active)
        o[(OH - 1) * OW + tx] = (hm1 + 3.0f * (h0 + h1)) * 0.015625f;
}

extern "C" void kernel_launch(void* const* d_in, const int* in_sizes, int n_in,
                              void* d_out, int out_size, void* d_ws, size_t ws_size,
                              hipStream_t stream) {
    const float* x = (const float*)d_in[0];
    float* out = (float*)d_out;
    const int n_imgs = 16 * 256;           // N*C
    hipLaunchKernelGGL(upfirdn2d_blur_kernel, dim3(n_imgs), dim3(128), 0, stream,
                       x, out);
}

// Round 2
// 459.597 us; speedup vs baseline: 1.0308x; 1.0308x over previous
//
#include <hip/hip_runtime.h>

// upfirdn2d depthwise 4x4 blur, kernel = outer([1,3,3,1],[1,3,3,1])/64.
// x: (16,256,128,128) f32 -> out: (16,256,127,127) f32, zero pad (1,1)/(1,1).
//
// v2: float4 loads (16 B/lane), horizontal halo via intra-wave __shfl,
// vertical 4-tap via rolling float4 registers. One block (128 thr) per image:
// lane c = tid&31 owns cols 4c..4c+3, split s = tid>>5 owns output rows
// 32s..32s+31 (3 h-rows of overlap between splits, ~6% redundant reads).
// 4096 blocks x 2 waves = 8192 waves = full 32 waves/CU.

#define IW 128
#define IH 128
#define OW 127
#define OH 127

__global__ __launch_bounds__(128)
void upfirdn2d_blur_v2(const float4* __restrict__ x, float* __restrict__ out) {
    const int tid = threadIdx.x;
    const int c   = tid & 31;        // column group: input cols 4c..4c+3
    const int s   = tid >> 5;        // row split: output rows 32s..32s+31
    const int img = blockIdx.x;      // n*C + c  (4096 images)

    const float4* __restrict__ in4 = x + (size_t)img * (IH * IW / 4);
    float*        __restrict__ o   = out + (size_t)img * (OH * OW);

    const float mL = (c > 0)  ? 1.0f : 0.0f;   // col 4c-1 valid?
    const float mR = (c < 31) ? 1.0f : 0.0f;   // cols 4c+4, 4c+5 valid?
    const int lm1 = (tid - 1) & 63;            // lane within wave
    const int lp1 = (tid + 1) & 63;

    // horizontal 4-tap (1,3,3,1 unnormalized) on 4 columns from one float4
    auto hrow = [&](int r) -> float4 {
        const float4 v = in4[r * (IW / 4) + c];
        const float l  = mL * __shfl(v.w, lm1, 64);   // col 4c-1
        const float r0 = mR * __shfl(v.x, lp1, 64);   // col 4c+4
        const float r1 = mR * __shfl(v.y, lp1, 64);   // col 4c+5
        float4 h;
        h.x = l   + 3.0f * (v.x + v.y) + v.z;
        h.y = v.x + 3.0f * (v.y + v.z) + v.w;
        h.z = v.y + 3.0f * (v.z + v.w) + r0;
        h.w = v.z + 3.0f * (v.w + r0)  + r1;
        return h;
    };

    const int y0 = 32 * s;

    // rolling vertical window: out[y] = (h[y-1] + 3h[y] + 3h[y+1] + h[y+2])/64
    float4 hm1 = hrow(y0 > 0 ? y0 - 1 : 0);
    const float mTop = (y0 > 0) ? 1.0f : 0.0f;       // h(-1) = 0 (top pad)
    hm1.x *= mTop; hm1.y *= mTop; hm1.z *= mTop; hm1.w *= mTop;
    float4 h0 = hrow(y0);
    float4 h1 = hrow(y0 + 1);

    #pragma unroll 4
    for (int i = 0; i < 32; ++i) {
        const int y  = y0 + i;
        const int r2 = y + 2;
        const float m2 = (r2 < IH) ? 1.0f : 0.0f;    // h(128) = 0 (bottom pad)
        float4 h2 = hrow(r2 < IH ? r2 : IH - 1);
        h2.x *= m2; h2.y *= m2; h2.z *= m2; h2.w *= m2;

        if (y < OH) {                                 // s==3 skips y==127
            float4 r;
            r.x = (hm1.x + 3.0f * (h0.x + h1.x) + h2.x) * 0.015625f;
            r.y = (hm1.y + 3.0f * (h0.y + h1.y) + h2.y) * 0.015625f;
            r.z = (hm1.z + 3.0f * (h0.z + h1.z) + h2.z) * 0.015625f;
            r.w = (hm1.w + 3.0f * (h0.w + h1.w) + h2.w) * 0.015625f;
            float* __restrict__ po = o + y * OW + 4 * c;
            po[0] = r.x;
            po[1] = r.y;
            po[2] = r.z;
            if (c < 31) po[3] = r.w;                  // col 127 doesn't exist
        }
        hm1 = h0; h0 = h1; h1 = h2;
    }
}

extern "C" void kernel_launch(void* const* d_in, const int* in_sizes, int n_in,
                              void* d_out, int out_size, void* d_ws, size_t ws_size,
                              hipStream_t stream) {
    const float4* x = (const float4*)d_in[0];
    float* out = (float*)d_out;
    const int n_imgs = 16 * 256;     // N*C
    hipLaunchKernelGGL(upfirdn2d_blur_v2, dim3(n_imgs), dim3(128), 0, stream,
                       x, out);
}